// Round 1
// baseline (3102.527 us; speedup 1.0000x reference)
//
#include <hip/hip_runtime.h>
#include <hip/hip_bf16.h>
#include <math.h>

#define BB 32
#define NN 128
#define DD 1024

// ---------------- cost kernel: cost[b][i][j] = ||pred[b,i]-tgt[b,j]||_2 (f64) ----------------
__global__ __launch_bounds__(128) void cost_kernel(const float* __restrict__ pred,
                                                   const float* __restrict__ tgt,
                                                   double* __restrict__ cost) {
  int blk = blockIdx.x;            // 0 .. BB*16-1
  int b = blk >> 4;
  int it = (blk & 15) << 3;        // 8 rows of the cost matrix per block
  const float* Ab = pred + ((size_t)b * NN + it) * DD;
  const float* Bb = tgt + (size_t)b * NN * DD;
  __shared__ float a_s[8 * DD];    // 32 KiB
  for (int t = threadIdx.x; t < 8 * DD / 4; t += 128) {
    ((float4*)a_s)[t] = ((const float4*)Ab)[t];
  }
  __syncthreads();
  const int j = threadIdx.x;       // column of the cost matrix = target row
  const float4* brow = (const float4*)(Bb + (size_t)j * DD);
  double acc[8];
#pragma unroll
  for (int r = 0; r < 8; r++) acc[r] = 0.0;
  for (int k4 = 0; k4 < DD / 4; k4++) {
    float4 bv = brow[k4];
#pragma unroll
    for (int r = 0; r < 8; r++) {
      float4 av = ((const float4*)(a_s + r * DD))[k4];
      double d0 = (double)av.x - (double)bv.x;
      double d1 = (double)av.y - (double)bv.y;
      double d2 = (double)av.z - (double)bv.z;
      double d3 = (double)av.w - (double)bv.w;
      acc[r] += d0 * d0 + d1 * d1 + d2 * d2 + d3 * d3;
    }
  }
#pragma unroll
  for (int r = 0; r < 8; r++) {
    cost[(((size_t)b * NN) + it + r) * NN + j] = sqrt(acc[r]);
  }
}

// ---------------- Hungarian (shortest augmenting path with potentials) ----------------
// One batch per block, one wave (64 lanes), 2 columns per lane.
// Mirrors the reference algorithm exactly (same arithmetic order, argmin
// tie-break to smallest column index).
__global__ __launch_bounds__(64) void hungarian_kernel(const double* __restrict__ cost,
                                                       int* __restrict__ colfor) {
  const int b = blockIdx.x;
  const double* C = cost + (size_t)b * NN * NN;
  const int lane = threadIdx.x;     // 0..63
  const int jA = lane + 1;          // 1-based columns owned by this lane
  const int jB = lane + 65;

  __shared__ double u[NN + 1];
  __shared__ int p[NN + 1];
  __shared__ int way[NN + 1];

  for (int t = lane; t <= NN; t += 64) { u[t] = 0.0; p[t] = 0; way[t] = 0; }
  double vA = 0.0, vB = 0.0;        // column potentials (register-resident)
  __syncthreads();

  for (int i = 1; i <= NN; i++) {
    if (lane == 0) p[0] = i;
    double minvA = 1e18, minvB = 1e18;
    int usedA = 0, usedB = 0;
    int rowA = 0, rowB = 0;
    int j0 = 0;
    __syncthreads();
    while (true) {
      int i0 = (j0 == 0) ? i : p[j0];
      if (j0 == jA) { usedA = 1; rowA = i0; }
      if (j0 == jB) { usedB = 1; rowB = i0; }
      double u_i0 = u[i0];
      const double* crow = C + (size_t)(i0 - 1) * NN;
      if (!usedA) {
        double cand = crow[lane] - u_i0 - vA;
        if (cand < minvA) { minvA = cand; way[jA] = j0; }
      }
      if (!usedB) {
        double cand = crow[lane + 64] - u_i0 - vB;
        if (cand < minvB) { minvB = cand; way[jB] = j0; }
      }
      // argmin over free columns, tie -> smallest column index
      double val; int idx;
      double aV = usedA ? 1e30 : minvA;
      double bV = usedB ? 1e30 : minvB;
      if (aV <= bV) { val = aV; idx = jA; } else { val = bV; idx = jB; }
#pragma unroll
      for (int off = 32; off > 0; off >>= 1) {
        double oval = __shfl_xor(val, off);
        int   oidx  = __shfl_xor(idx, off);
        if (oval < val || (oval == val && oidx < idx)) { val = oval; idx = oidx; }
      }
      double delta = val;
      int j1 = idx;
      // potential updates (distinct u[] addresses across lanes: matching rows unique)
      if (usedA) { u[rowA] += delta; vA -= delta; } else { minvA -= delta; }
      if (usedB) { u[rowB] += delta; vB -= delta; } else { minvB -= delta; }
      if (lane == 0) u[i] += delta;   // u[p[0]] = u[i]
      j0 = j1;
      int done = (p[j1] == 0);
      __syncthreads();                // u/way visible for next iter / augment
      if (done) break;
    }
    if (lane == 0) {                  // augment along way[] chain
      int jj = j0;
      while (jj) { int j1 = way[jj]; p[jj] = p[j1]; jj = j1; }
    }
    __syncthreads();
  }
  colfor[b * NN + (p[jA] - 1)] = jA - 1;
  colfor[b * NN + (p[jB] - 1)] = jB - 1;
}

// ---------------- node loss: sum (pred - tgt[col])^2, f64 partials per block ----------------
__global__ __launch_bounds__(256) void node_loss_kernel(const float* __restrict__ pred,
                                                        const float* __restrict__ tgt,
                                                        const int* __restrict__ col,
                                                        double* __restrict__ partial) {
  const size_t total = (size_t)BB * NN * (DD / 4);
  double s = 0.0;
  for (size_t idx = (size_t)blockIdx.x * blockDim.x + threadIdx.x; idx < total;
       idx += (size_t)gridDim.x * blockDim.x) {
    size_t k4 = idx & (DD / 4 - 1);
    size_t bi = idx / (DD / 4);
    int i = (int)(bi & (NN - 1));
    int b = (int)(bi >> 7);
    int c = col[b * NN + i];
    float4 pv = ((const float4*)pred)[idx];
    float4 tv = ((const float4*)(tgt + ((size_t)b * NN + c) * DD))[k4];
    float d0 = pv.x - tv.x, d1 = pv.y - tv.y, d2 = pv.z - tv.z, d3 = pv.w - tv.w;
    s += (double)d0 * d0 + (double)d1 * d1 + (double)d2 * d2 + (double)d3 * d3;
  }
  __shared__ double red[256];
  red[threadIdx.x] = s;
  __syncthreads();
  for (int off = 128; off > 0; off >>= 1) {
    if (threadIdx.x < off) red[threadIdx.x] += red[threadIdx.x + off];
    __syncthreads();
  }
  if (threadIdx.x == 0) partial[blockIdx.x] = red[0];
}

// ---------------- edge loss: sum (pred_adj - tgt_adj[col,col])^2 ----------------
__global__ __launch_bounds__(256) void edge_loss_kernel(const float* __restrict__ padj,
                                                        const float* __restrict__ tadj,
                                                        const int* __restrict__ col,
                                                        double* __restrict__ partial) {
  const size_t total = (size_t)BB * NN * NN;
  double s = 0.0;
  for (size_t idx = (size_t)blockIdx.x * blockDim.x + threadIdx.x; idx < total;
       idx += (size_t)gridDim.x * blockDim.x) {
    int j = (int)(idx & (NN - 1));
    size_t bi = idx >> 7;
    int i = (int)(bi & (NN - 1));
    int b = (int)(bi >> 7);
    int ci = col[b * NN + i];
    int cj = col[b * NN + j];
    float diff = padj[idx] - tadj[((size_t)b * NN + ci) * NN + cj];
    s += (double)diff * (double)diff;
  }
  __shared__ double red[256];
  red[threadIdx.x] = s;
  __syncthreads();
  for (int off = 128; off > 0; off >>= 1) {
    if (threadIdx.x < off) red[threadIdx.x] += red[threadIdx.x + off];
    __syncthreads();
  }
  if (threadIdx.x == 0) partial[blockIdx.x] = red[0];
}

// ---------------- finalize: deterministic sum of partials -> d_out[2] ----------------
__global__ __launch_bounds__(256) void finalize_kernel(const double* __restrict__ nodeP, int nNode,
                                                       const double* __restrict__ edgeP, int nEdge,
                                                       float* __restrict__ out) {
  __shared__ double red[256];
  double s = 0.0;
  for (int t = threadIdx.x; t < nNode; t += 256) s += nodeP[t];
  red[threadIdx.x] = s;
  __syncthreads();
  for (int off = 128; off > 0; off >>= 1) {
    if (threadIdx.x < off) red[threadIdx.x] += red[threadIdx.x + off];
    __syncthreads();
  }
  double nodeSum = red[0];
  __syncthreads();
  s = 0.0;
  for (int t = threadIdx.x; t < nEdge; t += 256) s += edgeP[t];
  red[threadIdx.x] = s;
  __syncthreads();
  for (int off = 128; off > 0; off >>= 1) {
    if (threadIdx.x < off) red[threadIdx.x] += red[threadIdx.x + off];
    __syncthreads();
  }
  if (threadIdx.x == 0) {
    out[0] = (float)(nodeSum / (double)(NN * DD));
    out[1] = (float)(red[0] / (double)(NN * NN));
  }
}

extern "C" void kernel_launch(void* const* d_in, const int* in_sizes, int n_in,
                              void* d_out, int out_size, void* d_ws, size_t ws_size,
                              hipStream_t stream) {
  const float* pred_nodes   = (const float*)d_in[0];
  const float* target_nodes = (const float*)d_in[1];
  const float* pred_adj     = (const float*)d_in[2];
  const float* target_adj   = (const float*)d_in[3];
  float* out = (float*)d_out;

  char* ws = (char*)d_ws;
  double* cost = (double*)ws;                                   // 32*128*128*8 = 4 MiB
  size_t off = (size_t)BB * NN * NN * sizeof(double);
  int* col = (int*)(ws + off);                                  // 16 KiB
  off += (size_t)BB * NN * sizeof(int);
  double* nodeP = (double*)(ws + off);                          // 512 doubles
  double* edgeP = nodeP + 512;                                  // 128 doubles

  cost_kernel<<<BB * 16, 128, 0, stream>>>(pred_nodes, target_nodes, cost);
  hungarian_kernel<<<BB, 64, 0, stream>>>(cost, col);
  node_loss_kernel<<<512, 256, 0, stream>>>(pred_nodes, target_nodes, col, nodeP);
  edge_loss_kernel<<<128, 256, 0, stream>>>(pred_adj, target_adj, col, edgeP);
  finalize_kernel<<<1, 256, 0, stream>>>(nodeP, 512, edgeP, 128, out);
}

// Round 2
// 1177.835 us; speedup vs baseline: 2.6341x; 2.6341x over previous
//
#include <hip/hip_runtime.h>
#include <hip/hip_bf16.h>
#include <math.h>

#define BB 32
#define NN 128
#define DD 1024
#define INF64 1e30

// ---------------- cost kernel: cost[b][i][j] = ||pred[b,i]-tgt[b,j]||_2 (f64) ----------------
__global__ __launch_bounds__(128) void cost_kernel(const float* __restrict__ pred,
                                                   const float* __restrict__ tgt,
                                                   double* __restrict__ cost) {
  int blk = blockIdx.x;            // 0 .. BB*16-1
  int b = blk >> 4;
  int it = (blk & 15) << 3;        // 8 rows of the cost matrix per block
  const float* Ab = pred + ((size_t)b * NN + it) * DD;
  const float* Bb = tgt + (size_t)b * NN * DD;
  __shared__ float a_s[8 * DD];    // 32 KiB
  for (int t = threadIdx.x; t < 8 * DD / 4; t += 128) {
    ((float4*)a_s)[t] = ((const float4*)Ab)[t];
  }
  __syncthreads();
  const int j = threadIdx.x;       // column of the cost matrix = target row
  const float4* brow = (const float4*)(Bb + (size_t)j * DD);
  double acc[8];
#pragma unroll
  for (int r = 0; r < 8; r++) acc[r] = 0.0;
  for (int k4 = 0; k4 < DD / 4; k4++) {
    float4 bv = brow[k4];
#pragma unroll
    for (int r = 0; r < 8; r++) {
      float4 av = ((const float4*)(a_s + r * DD))[k4];
      double d0 = (double)av.x - (double)bv.x;
      double d1 = (double)av.y - (double)bv.y;
      double d2 = (double)av.z - (double)bv.z;
      double d3 = (double)av.w - (double)bv.w;
      acc[r] += d0 * d0 + d1 * d1 + d2 * d2 + d3 * d3;
    }
  }
#pragma unroll
  for (int r = 0; r < 8; r++) {
    cost[(((size_t)b * NN) + it + r) * NN + j] = sqrt(acc[r]);
  }
}

// ---------------- cross-lane helpers (wave64, all lanes active) ----------------
union f64u { double d; unsigned int i[2]; };

__device__ __forceinline__ double readlane_f64(double x, int lane) {
  f64u u; u.d = x;
  f64u v;
  v.i[0] = (unsigned)__builtin_amdgcn_readlane((int)u.i[0], lane);
  v.i[1] = (unsigned)__builtin_amdgcn_readlane((int)u.i[1], lane);
  return v.d;
}

// value of a column/row-indexed register pair: a holds indices 1..64 (lane+1),
// b holds 65..128 (lane+65). idx is 1-based, wave-uniform.
__device__ __forceinline__ double readpair_f64(double a, double b, int idx) {
  int l = (idx - 1) & 63;
  double ra = readlane_f64(a, l);
  double rb = readlane_f64(b, l);
  return ((idx - 1) >> 6) ? rb : ra;
}

__device__ __forceinline__ int readpair_i32(int a, int b, int idx) {
  int l = (idx - 1) & 63;
  int ra = __builtin_amdgcn_readlane(a, l);
  int rb = __builtin_amdgcn_readlane(b, l);
  return ((idx - 1) >> 6) ? rb : ra;
}

// DPP f64 min step: r = min(r, dpp_move(r)); invalid source lanes keep old (identity).
#define DPP_MIN_STEP(r, CTRL)                                                        \
  do {                                                                               \
    f64u _t; _t.d = (r);                                                             \
    f64u _s;                                                                         \
    _s.i[0] = (unsigned)__builtin_amdgcn_update_dpp((int)_t.i[0], (int)_t.i[0],      \
                                                    (CTRL), 0xF, 0xF, false);        \
    _s.i[1] = (unsigned)__builtin_amdgcn_update_dpp((int)_t.i[1], (int)_t.i[1],      \
                                                    (CTRL), 0xF, 0xF, false);        \
    (r) = fmin((r), _s.d);                                                           \
  } while (0)

// ---------------- Hungarian (shortest augmenting path with potentials) ----------------
// One batch per block, one wave. Cost matrix in LDS (128 KiB). All state
// (u, v, p, way, minv) register-resident; cross-lane via readlane/ballot/DPP.
// Arithmetic order and tie-breaks mirror the f64 reference exactly.
__global__ __launch_bounds__(64) void hungarian_kernel(const double* __restrict__ cost,
                                                       int* __restrict__ colfor) {
  extern __shared__ double lds[];   // [NN][NN] doubles = 128 KiB
  const int b = blockIdx.x;
  const double* C = cost + (size_t)b * NN * NN;
  const int lane = threadIdx.x;     // 0..63
  const int jA = lane + 1;          // 1-based columns owned by this lane
  const int jB = lane + 65;

  // preload full cost matrix to LDS (16B per lane per iteration, coalesced)
  {
    const double2* src = (const double2*)C;
    double2* dst = (double2*)lds;
#pragma unroll 8
    for (int t = lane; t < NN * NN / 2; t += 64) dst[t] = src[t];
  }
  __syncthreads();

  double uA = 0.0, uB = 0.0;        // u for rows lane+1, lane+65
  double vA = 0.0, vB = 0.0;        // v for cols jA, jB
  int pA = 0, pB = 0;               // p for cols jA, jB (matched row, 0 = free)

  for (int i = 1; i <= NN; i++) {
    double minvA = INF64, minvB = INF64;
    int wayA = 0, wayB = 0;
    int usedA = 0, usedB = 0;
    unsigned long long usedRowLo = 0ull, usedRowHi = 0ull;  // rows 1..64 / 65..128
    int j0 = 0;
    int i0 = i;
    int jfin;
    while (true) {
      // mark column j0 used (j0==0 virtual column: no lane owns it)
      usedA |= (j0 == jA);
      usedB |= (j0 == jB);
      // add row i0 to used-row set (wave-uniform masks)
      if (i0 <= 64) usedRowLo |= 1ull << (i0 - 1); else usedRowHi |= 1ull << (i0 - 65);
      // u[i0] (value through previous iteration)
      double u_i0 = readpair_f64(uA, uB, i0);
      // cost row from LDS
      const double* crow = lds + (size_t)(i0 - 1) * NN;
      double cA = crow[lane];
      double cB = crow[lane + 64];
      double candA = cA - u_i0 - vA;
      double candB = cB - u_i0 - vB;
      if (!usedA && candA < minvA) { minvA = candA; wayA = j0; }
      if (!usedB && candB < minvB) { minvB = candB; wayB = j0; }
      // argmin over free columns, tie -> smallest column index
      double mA = usedA ? INF64 : minvA;
      double mB = usedB ? INF64 : minvB;
      double r = fmin(mA, mB);
      DPP_MIN_STEP(r, 0x111);  // row_shr:1
      DPP_MIN_STEP(r, 0x112);  // row_shr:2
      DPP_MIN_STEP(r, 0x114);  // row_shr:4
      DPP_MIN_STEP(r, 0x118);  // row_shr:8
      DPP_MIN_STEP(r, 0x142);  // row_bcast:15
      DPP_MIN_STEP(r, 0x143);  // row_bcast:31  -> lane 63 holds global min
      double delta = readlane_f64(r, 63);
      // smallest free column whose minv equals the min (A group = cols 1..64 first)
      unsigned long long ba = __ballot(mA == delta);
      unsigned long long bb = __ballot(mB == delta);
      int j1 = ba ? (int)(__builtin_ctzll(ba) + 1) : (int)(__builtin_ctzll(bb) + 65);
      // updates (reference order): u[p[used]] += delta; v[used] -= delta; minv[~used] -= delta
      if ((usedRowLo >> lane) & 1ull) uA += delta;
      if ((usedRowHi >> lane) & 1ull) uB += delta;
      if (usedA) vA -= delta; else minvA -= delta;
      if (usedB) vB -= delta; else minvB -= delta;
      // advance
      int pj1 = readpair_i32(pA, pB, j1);
      j0 = j1;
      if (pj1 == 0) { jfin = j1; break; }
      i0 = pj1;
    }
    // augment: wave-uniform walk along way[] chain
    int j = jfin;
    while (j) {
      int wj = readpair_i32(wayA, wayB, j);           // way[j]
      int pn = (wj == 0) ? i : readpair_i32(pA, pB, wj);  // p[way[j]] (pre-update)
      if (j == jA) pA = pn;
      if (j == jB) pB = pn;
      j = wj;
    }
  }
  colfor[b * NN + (pA - 1)] = jA - 1;
  colfor[b * NN + (pB - 1)] = jB - 1;
}

// ---------------- node loss: sum (pred - tgt[col])^2, f64 partials per block ----------------
__global__ __launch_bounds__(256) void node_loss_kernel(const float* __restrict__ pred,
                                                        const float* __restrict__ tgt,
                                                        const int* __restrict__ col,
                                                        double* __restrict__ partial) {
  const size_t total = (size_t)BB * NN * (DD / 4);
  double s = 0.0;
  for (size_t idx = (size_t)blockIdx.x * blockDim.x + threadIdx.x; idx < total;
       idx += (size_t)gridDim.x * blockDim.x) {
    size_t k4 = idx & (DD / 4 - 1);
    size_t bi = idx / (DD / 4);
    int i = (int)(bi & (NN - 1));
    int b = (int)(bi >> 7);
    int c = col[b * NN + i];
    float4 pv = ((const float4*)pred)[idx];
    float4 tv = ((const float4*)(tgt + ((size_t)b * NN + c) * DD))[k4];
    float d0 = pv.x - tv.x, d1 = pv.y - tv.y, d2 = pv.z - tv.z, d3 = pv.w - tv.w;
    s += (double)d0 * d0 + (double)d1 * d1 + (double)d2 * d2 + (double)d3 * d3;
  }
  __shared__ double red[256];
  red[threadIdx.x] = s;
  __syncthreads();
  for (int off = 128; off > 0; off >>= 1) {
    if (threadIdx.x < off) red[threadIdx.x] += red[threadIdx.x + off];
    __syncthreads();
  }
  if (threadIdx.x == 0) partial[blockIdx.x] = red[0];
}

// ---------------- edge loss: sum (pred_adj - tgt_adj[col,col])^2 ----------------
__global__ __launch_bounds__(256) void edge_loss_kernel(const float* __restrict__ padj,
                                                        const float* __restrict__ tadj,
                                                        const int* __restrict__ col,
                                                        double* __restrict__ partial) {
  const size_t total = (size_t)BB * NN * NN;
  double s = 0.0;
  for (size_t idx = (size_t)blockIdx.x * blockDim.x + threadIdx.x; idx < total;
       idx += (size_t)gridDim.x * blockDim.x) {
    int j = (int)(idx & (NN - 1));
    size_t bi = idx >> 7;
    int i = (int)(bi & (NN - 1));
    int b = (int)(bi >> 7);
    int ci = col[b * NN + i];
    int cj = col[b * NN + j];
    float diff = padj[idx] - tadj[((size_t)b * NN + ci) * NN + cj];
    s += (double)diff * (double)diff;
  }
  __shared__ double red[256];
  red[threadIdx.x] = s;
  __syncthreads();
  for (int off = 128; off > 0; off >>= 1) {
    if (threadIdx.x < off) red[threadIdx.x] += red[threadIdx.x + off];
    __syncthreads();
  }
  if (threadIdx.x == 0) partial[blockIdx.x] = red[0];
}

// ---------------- finalize: deterministic sum of partials -> d_out[2] ----------------
__global__ __launch_bounds__(256) void finalize_kernel(const double* __restrict__ nodeP, int nNode,
                                                       const double* __restrict__ edgeP, int nEdge,
                                                       float* __restrict__ out) {
  __shared__ double red[256];
  double s = 0.0;
  for (int t = threadIdx.x; t < nNode; t += 256) s += nodeP[t];
  red[threadIdx.x] = s;
  __syncthreads();
  for (int off = 128; off > 0; off >>= 1) {
    if (threadIdx.x < off) red[threadIdx.x] += red[threadIdx.x + off];
    __syncthreads();
  }
  double nodeSum = red[0];
  __syncthreads();
  s = 0.0;
  for (int t = threadIdx.x; t < nEdge; t += 256) s += edgeP[t];
  red[threadIdx.x] = s;
  __syncthreads();
  for (int off = 128; off > 0; off >>= 1) {
    if (threadIdx.x < off) red[threadIdx.x] += red[threadIdx.x + off];
    __syncthreads();
  }
  if (threadIdx.x == 0) {
    out[0] = (float)(nodeSum / (double)(NN * DD));
    out[1] = (float)(red[0] / (double)(NN * NN));
  }
}

extern "C" void kernel_launch(void* const* d_in, const int* in_sizes, int n_in,
                              void* d_out, int out_size, void* d_ws, size_t ws_size,
                              hipStream_t stream) {
  const float* pred_nodes   = (const float*)d_in[0];
  const float* target_nodes = (const float*)d_in[1];
  const float* pred_adj     = (const float*)d_in[2];
  const float* target_adj   = (const float*)d_in[3];
  float* out = (float*)d_out;

  char* ws = (char*)d_ws;
  double* cost = (double*)ws;                                   // 32*128*128*8 = 4 MiB
  size_t off = (size_t)BB * NN * NN * sizeof(double);
  int* col = (int*)(ws + off);                                  // 16 KiB
  off += (size_t)BB * NN * sizeof(int);
  double* nodeP = (double*)(ws + off);                          // 512 doubles
  double* edgeP = nodeP + 512;                                  // 128 doubles

  cost_kernel<<<BB * 16, 128, 0, stream>>>(pred_nodes, target_nodes, cost);
  hungarian_kernel<<<BB, 64, 131072, stream>>>(cost, col);      // 128 KiB dynamic LDS
  node_loss_kernel<<<512, 256, 0, stream>>>(pred_nodes, target_nodes, col, nodeP);
  edge_loss_kernel<<<128, 256, 0, stream>>>(pred_adj, target_adj, col, edgeP);
  finalize_kernel<<<1, 256, 0, stream>>>(nodeP, 512, edgeP, 128, out);
}

// Round 3
// 831.927 us; speedup vs baseline: 3.7293x; 1.4158x over previous
//
#include <hip/hip_runtime.h>
#include <hip/hip_bf16.h>
#include <math.h>

#define BB 32
#define NN 128
#define DD 1024
#define INF64 1e30

// ---------------- cost kernel: cost[b][i][j] = ||pred[b,i]-tgt[b,j]||_2 (f64) ----------------
__global__ __launch_bounds__(128) void cost_kernel(const float* __restrict__ pred,
                                                   const float* __restrict__ tgt,
                                                   double* __restrict__ cost) {
  int blk = blockIdx.x;            // 0 .. BB*16-1
  int b = blk >> 4;
  int it = (blk & 15) << 3;        // 8 rows of the cost matrix per block
  const float* Ab = pred + ((size_t)b * NN + it) * DD;
  const float* Bb = tgt + (size_t)b * NN * DD;
  __shared__ float a_s[8 * DD];    // 32 KiB
  for (int t = threadIdx.x; t < 8 * DD / 4; t += 128) {
    ((float4*)a_s)[t] = ((const float4*)Ab)[t];
  }
  __syncthreads();
  const int j = threadIdx.x;       // column of the cost matrix = target row
  const float4* brow = (const float4*)(Bb + (size_t)j * DD);
  double acc[8];
#pragma unroll
  for (int r = 0; r < 8; r++) acc[r] = 0.0;
  for (int k4 = 0; k4 < DD / 4; k4++) {
    float4 bv = brow[k4];
#pragma unroll
    for (int r = 0; r < 8; r++) {
      float4 av = ((const float4*)(a_s + r * DD))[k4];
      double d0 = (double)av.x - (double)bv.x;
      double d1 = (double)av.y - (double)bv.y;
      double d2 = (double)av.z - (double)bv.z;
      double d3 = (double)av.w - (double)bv.w;
      acc[r] += d0 * d0 + d1 * d1 + d2 * d2 + d3 * d3;
    }
  }
#pragma unroll
  for (int r = 0; r < 8; r++) {
    cost[(((size_t)b * NN) + it + r) * NN + j] = sqrt(acc[r]);
  }
}

// ---------------- cross-lane helpers (wave64, all lanes active) ----------------
union f64u { double d; unsigned int i[2]; };

__device__ __forceinline__ double readlane_f64(double x, int lane) {
  f64u u; u.d = x;
  f64u v;
  v.i[0] = (unsigned)__builtin_amdgcn_readlane((int)u.i[0], lane);
  v.i[1] = (unsigned)__builtin_amdgcn_readlane((int)u.i[1], lane);
  return v.d;
}

// value of a column/row-indexed register pair: a holds indices 1..64 (lane+1),
// b holds 65..128 (lane+65). idx is 1-based, wave-uniform.
__device__ __forceinline__ double readpair_f64(double a, double b, int idx) {
  int l = (idx - 1) & 63;
  double ra = readlane_f64(a, l);
  double rb = readlane_f64(b, l);
  return ((idx - 1) >> 6) ? rb : ra;
}

__device__ __forceinline__ int readpair_i32(int a, int b, int idx) {
  int l = (idx - 1) & 63;
  int ra = __builtin_amdgcn_readlane(a, l);
  int rb = __builtin_amdgcn_readlane(b, l);
  return ((idx - 1) >> 6) ? rb : ra;
}

// pack nonnegative f64 value + 7-bit index into one sortable f64 key:
// positive doubles order like their u64 bit patterns; low 7 mantissa bits
// carry the index (perturbs value by <= 2^-45 rel, harmless to optimality,
// gives deterministic smallest-index tie-break).
__device__ __forceinline__ double pack_key(double m, int idx) {
  unsigned long long bits = __double_as_longlong(fmax(m, 0.0));
  bits = (bits & ~127ull) | (unsigned long long)idx;
  return __longlong_as_double(bits);
}

// DPP f64 min step: r = min(r, dpp_move(r)); invalid source lanes keep old (identity).
#define DPP_MIN_STEP(r, CTRL)                                                        \
  do {                                                                               \
    f64u _t; _t.d = (r);                                                             \
    f64u _s;                                                                         \
    _s.i[0] = (unsigned)__builtin_amdgcn_update_dpp((int)_t.i[0], (int)_t.i[0],      \
                                                    (CTRL), 0xF, 0xF, false);        \
    _s.i[1] = (unsigned)__builtin_amdgcn_update_dpp((int)_t.i[1], (int)_t.i[1],      \
                                                    (CTRL), 0xF, 0xF, false);        \
    (r) = fmin((r), _s.d);                                                           \
  } while (0)

// ---------------- Hungarian: JV column-reduction seed + shortest augmenting path ----------------
// One batch per block, one wave. Cost matrix in LDS (128 KiB). All state
// (u, v, p, way, minv) register-resident; cross-lane via readlane/DPP.
// Seeded with v[j] = column minima + greedy tight matching (dual-feasible,
// complementary), then exact Dijkstra-SAP for the remaining free rows.
// Result: the exact optimal assignment (a.s. unique for continuous costs).
__global__ __launch_bounds__(64) void hungarian_kernel(const double* __restrict__ cost,
                                                       int* __restrict__ colfor) {
  extern __shared__ double lds[];   // [NN][NN] doubles = 128 KiB
  const int b = blockIdx.x;
  const double* C = cost + (size_t)b * NN * NN;
  const int lane = threadIdx.x;     // 0..63
  const int jA = lane + 1;          // 1-based columns owned by this lane
  const int jB = lane + 65;

  // preload full cost matrix to LDS (16B per lane per iteration, coalesced)
  {
    const double2* src = (const double2*)C;
    double2* dst = (double2*)lds;
#pragma unroll 8
    for (int t = lane; t < NN * NN / 2; t += 64) dst[t] = src[t];
  }
  __syncthreads();

  // ---- column reduction: v[j] = min_i C[i][j], arg = its row (ties -> smallest row) ----
  double vA = INF64, vB = INF64;
  int argA = 0, argB = 0;
#pragma unroll 4
  for (int i = 0; i < NN; i++) {
    double cA = lds[(size_t)i * NN + lane];
    double cB = lds[(size_t)i * NN + lane + 64];
    if (cA < vA) { vA = cA; argA = i + 1; }
    if (cB < vB) { vB = cB; argB = i + 1; }
  }

  // ---- greedy tight matching: columns ascending, assign argmin row if free ----
  unsigned long long asgLo = 0ull, asgHi = 0ull;   // rows matched by greedy
  int pA = 0, pB = 0;               // p for cols jA, jB (matched row, 0 = free)
  for (int j = 1; j <= NN; j++) {
    int ar = readpair_i32(argA, argB, j);
    bool freeRow = (ar <= 64) ? !((asgLo >> (ar - 1)) & 1ull)
                              : !((asgHi >> (ar - 65)) & 1ull);
    if (freeRow) {
      if (ar <= 64) asgLo |= 1ull << (ar - 1); else asgHi |= 1ull << (ar - 65);
      if (j == jA) pA = ar;
      if (j == jB) pB = ar;
    }
  }

  double uA = 0.0, uB = 0.0;        // u for rows lane+1, lane+65

  // ---- Dijkstra-SAP for rows left free by the greedy phase ----
  for (int i = 1; i <= NN; i++) {
    bool seeded = (i <= 64) ? ((asgLo >> (i - 1)) & 1ull)
                            : ((asgHi >> (i - 65)) & 1ull);
    if (seeded) continue;

    double minvA = INF64, minvB = INF64;
    int wayA = 0, wayB = 0;
    int usedA = 0, usedB = 0;
    unsigned long long usedRowLo = 0ull, usedRowHi = 0ull;
    int j0 = 0;
    int i0 = i;
    int jfin;
    while (true) {
      usedA |= (j0 == jA);
      usedB |= (j0 == jB);
      if (i0 <= 64) usedRowLo |= 1ull << (i0 - 1); else usedRowHi |= 1ull << (i0 - 65);
      double u_i0 = readpair_f64(uA, uB, i0);
      const double* crow = lds + (size_t)(i0 - 1) * NN;
      double cA = crow[lane];
      double cB = crow[lane + 64];
      double candA = cA - u_i0 - vA;
      double candB = cB - u_i0 - vB;
      if (!usedA && candA < minvA) { minvA = candA; wayA = j0; }
      if (!usedB && candB < minvB) { minvB = candB; wayB = j0; }
      // fused value+index argmin over free columns
      double kA = pack_key(usedA ? INF64 : minvA, lane);
      double kB = pack_key(usedB ? INF64 : minvB, lane + 64);
      double r = fmin(kA, kB);
      DPP_MIN_STEP(r, 0x111);  // row_shr:1
      DPP_MIN_STEP(r, 0x112);  // row_shr:2
      DPP_MIN_STEP(r, 0x114);  // row_shr:4
      DPP_MIN_STEP(r, 0x118);  // row_shr:8
      DPP_MIN_STEP(r, 0x142);  // row_bcast:15
      DPP_MIN_STEP(r, 0x143);  // row_bcast:31  -> lane 63 holds global min
      double rmin = readlane_f64(r, 63);
      unsigned long long bits = __double_as_longlong(rmin);
      int j1 = (int)(bits & 127ull) + 1;
      double delta = __longlong_as_double(bits & ~127ull);
      // dual updates: u[tree rows] += delta; v[used cols] -= delta; minv[free] -= delta
      if ((usedRowLo >> lane) & 1ull) uA += delta;
      if ((usedRowHi >> lane) & 1ull) uB += delta;
      if (usedA) vA -= delta; else minvA -= delta;
      if (usedB) vB -= delta; else minvB -= delta;
      // advance
      int pj1 = readpair_i32(pA, pB, j1);
      j0 = j1;
      if (pj1 == 0) { jfin = j1; break; }
      i0 = pj1;
    }
    // augment: wave-uniform walk along way[] chain
    int j = jfin;
    while (j) {
      int wj = readpair_i32(wayA, wayB, j);               // way[j]
      int pn = (wj == 0) ? i : readpair_i32(pA, pB, wj);  // p[way[j]] (pre-update)
      if (j == jA) pA = pn;
      if (j == jB) pB = pn;
      j = wj;
    }
  }
  colfor[b * NN + (pA - 1)] = jA - 1;
  colfor[b * NN + (pB - 1)] = jB - 1;
}

// ---------------- node loss: sum (pred - tgt[col])^2, f64 partials per block ----------------
__global__ __launch_bounds__(256) void node_loss_kernel(const float* __restrict__ pred,
                                                        const float* __restrict__ tgt,
                                                        const int* __restrict__ col,
                                                        double* __restrict__ partial) {
  const size_t total = (size_t)BB * NN * (DD / 4);
  double s = 0.0;
  for (size_t idx = (size_t)blockIdx.x * blockDim.x + threadIdx.x; idx < total;
       idx += (size_t)gridDim.x * blockDim.x) {
    size_t k4 = idx & (DD / 4 - 1);
    size_t bi = idx / (DD / 4);
    int i = (int)(bi & (NN - 1));
    int b = (int)(bi >> 7);
    int c = col[b * NN + i];
    float4 pv = ((const float4*)pred)[idx];
    float4 tv = ((const float4*)(tgt + ((size_t)b * NN + c) * DD))[k4];
    float d0 = pv.x - tv.x, d1 = pv.y - tv.y, d2 = pv.z - tv.z, d3 = pv.w - tv.w;
    s += (double)d0 * d0 + (double)d1 * d1 + (double)d2 * d2 + (double)d3 * d3;
  }
  __shared__ double red[256];
  red[threadIdx.x] = s;
  __syncthreads();
  for (int off = 128; off > 0; off >>= 1) {
    if (threadIdx.x < off) red[threadIdx.x] += red[threadIdx.x + off];
    __syncthreads();
  }
  if (threadIdx.x == 0) partial[blockIdx.x] = red[0];
}

// ---------------- edge loss: sum (pred_adj - tgt_adj[col,col])^2 ----------------
__global__ __launch_bounds__(256) void edge_loss_kernel(const float* __restrict__ padj,
                                                        const float* __restrict__ tadj,
                                                        const int* __restrict__ col,
                                                        double* __restrict__ partial) {
  const size_t total = (size_t)BB * NN * NN;
  double s = 0.0;
  for (size_t idx = (size_t)blockIdx.x * blockDim.x + threadIdx.x; idx < total;
       idx += (size_t)gridDim.x * blockDim.x) {
    int j = (int)(idx & (NN - 1));
    size_t bi = idx >> 7;
    int i = (int)(bi & (NN - 1));
    int b = (int)(bi >> 7);
    int ci = col[b * NN + i];
    int cj = col[b * NN + j];
    float diff = padj[idx] - tadj[((size_t)b * NN + ci) * NN + cj];
    s += (double)diff * (double)diff;
  }
  __shared__ double red[256];
  red[threadIdx.x] = s;
  __syncthreads();
  for (int off = 128; off > 0; off >>= 1) {
    if (threadIdx.x < off) red[threadIdx.x] += red[threadIdx.x + off];
    __syncthreads();
  }
  if (threadIdx.x == 0) partial[blockIdx.x] = red[0];
}

// ---------------- finalize: deterministic sum of partials -> d_out[2] ----------------
__global__ __launch_bounds__(256) void finalize_kernel(const double* __restrict__ nodeP, int nNode,
                                                       const double* __restrict__ edgeP, int nEdge,
                                                       float* __restrict__ out) {
  __shared__ double red[256];
  double s = 0.0;
  for (int t = threadIdx.x; t < nNode; t += 256) s += nodeP[t];
  red[threadIdx.x] = s;
  __syncthreads();
  for (int off = 128; off > 0; off >>= 1) {
    if (threadIdx.x < off) red[threadIdx.x] += red[threadIdx.x + off];
    __syncthreads();
  }
  double nodeSum = red[0];
  __syncthreads();
  s = 0.0;
  for (int t = threadIdx.x; t < nEdge; t += 256) s += edgeP[t];
  red[threadIdx.x] = s;
  __syncthreads();
  for (int off = 128; off > 0; off >>= 1) {
    if (threadIdx.x < off) red[threadIdx.x] += red[threadIdx.x + off];
    __syncthreads();
  }
  if (threadIdx.x == 0) {
    out[0] = (float)(nodeSum / (double)(NN * DD));
    out[1] = (float)(red[0] / (double)(NN * NN));
  }
}

extern "C" void kernel_launch(void* const* d_in, const int* in_sizes, int n_in,
                              void* d_out, int out_size, void* d_ws, size_t ws_size,
                              hipStream_t stream) {
  const float* pred_nodes   = (const float*)d_in[0];
  const float* target_nodes = (const float*)d_in[1];
  const float* pred_adj     = (const float*)d_in[2];
  const float* target_adj   = (const float*)d_in[3];
  float* out = (float*)d_out;

  char* ws = (char*)d_ws;
  double* cost = (double*)ws;                                   // 32*128*128*8 = 4 MiB
  size_t off = (size_t)BB * NN * NN * sizeof(double);
  int* col = (int*)(ws + off);                                  // 16 KiB
  off += (size_t)BB * NN * sizeof(int);
  double* nodeP = (double*)(ws + off);                          // 512 doubles
  double* edgeP = nodeP + 512;                                  // 128 doubles

  cost_kernel<<<BB * 16, 128, 0, stream>>>(pred_nodes, target_nodes, cost);
  hungarian_kernel<<<BB, 64, 131072, stream>>>(cost, col);      // 128 KiB dynamic LDS
  node_loss_kernel<<<512, 256, 0, stream>>>(pred_nodes, target_nodes, col, nodeP);
  edge_loss_kernel<<<128, 256, 0, stream>>>(pred_adj, target_adj, col, edgeP);
  finalize_kernel<<<1, 256, 0, stream>>>(nodeP, 512, edgeP, 128, out);
}